// Round 15
// baseline (977.676 us; speedup 1.0000x reference)
//
// GatedTransformerXLLayer — MI355X (gfx950) — round 15 (base r14 = 977us):
//   1) fattn: T5 s_setprio(1) around QK/band/PV MFMA clusters (m191: attn
//      +4-7%; fattn is latency-bound w/ 2 blocks/CU -> scheduler arbitrage).
//   2) Psc stride 164->168: restores 16B alignment of PV f16x8 reads
//      (328B row stride forced split reads); 336B = 21x16.
//   3) o1 kept h16 through gate2 (gruo_ln writes h16; gate2 reads h16):
//      -48MB HBM traffic. Error <=5e-4 vs 0.084 threshold.
//   4) cast/xcast/addbias merged into one segmented prep2_k (-2 launches).
//
// D=1024 H=16 HD=64 HID=4096 CUR=512 PREV=512 FULL=1024 BS=16

#include <hip/hip_runtime.h>
#include <stdint.h>

typedef _Float16 h16;
typedef __attribute__((ext_vector_type(8))) _Float16 f16x8;
typedef __attribute__((ext_vector_type(4))) _Float16 f16x4;
typedef __attribute__((ext_vector_type(4))) float f32x4;

enum { F_OBF = 1, F_BIAS = 2, F_RELU = 4, F_ACC = 8, F_DUAL = 16 };

#define BARRIER_MEM                                  \
  do {                                               \
    asm volatile("" ::: "memory");                   \
    __builtin_amdgcn_s_barrier();                    \
    asm volatile("" ::: "memory");                   \
  } while (0)

static __device__ __forceinline__ void gload16(const void* g, void* l) {
  __builtin_amdgcn_global_load_lds((__attribute__((address_space(1))) void*)g,
                                   (__attribute__((address_space(3))) void*)l,
                                   16, 0, 0);
}

// ---------------------------------------------------------------------------
// gemm2_k: C = A(M x K) @ Bt(N x K)^T, 256 x BN tile, 8-phase pipeline
// (T2+T3+T4+T5). Grid: 1D nwg = (M/256)*(N/BN), nwg % 8 == 0, block 512.
// ---------------------------------------------------------------------------
template <int BN, int FLAGS>
__global__ __launch_bounds__(512) void gemm2_k(
    const h16* __restrict__ A, const h16* __restrict__ B,
    void* __restrict__ Cv, const float* __restrict__ bias,
    int K, int lda, int ldb, int ldc, int gm,
    void* __restrict__ C2v, const float* __restrict__ bias2) {
  constexpr int NH = BN / 128;
  constexpr int WN = BN / 4;
  __shared__ h16 Al[2][256][64];
  __shared__ h16 Bl[2][BN][64];

  const int tid = threadIdx.x, lane = tid & 63, wid = tid >> 6;
  const int wr = wid >> 2, wn = wid & 3;
  const int ar = lane & 15, q4 = lane >> 4;

  const int nwg = gridDim.x, cpx = nwg >> 3;
  const int bid = (blockIdx.x & 7) * cpx + (blockIdx.x >> 3);
  const int mx = bid % gm, ny = bid / gm;

  const h16* Ab = A + (long)mx * 256 * lda;
  const h16* Bb = B + (long)ny * BN * ldb;

  auto stageA = [&](int buf, int half, int k0) {
#pragma unroll
    for (int l = 0; l < 2; ++l) {
      const int idx = l * 512 + tid;
      const int row = half * 128 + (idx >> 3), sl = idx & 7;
      gload16(Ab + (long)row * lda + k0 + (sl ^ (row & 7)) * 8,
              (char*)&Al[buf][0][0] + (half * 1024 + l * 512 + wid * 64) * 16);
    }
  };
  auto stageB = [&](int buf, int half, int k0) {
#pragma unroll
    for (int l = 0; l < NH; ++l) {
      const int idx = l * 512 + tid;
      const int row = half * (BN / 2) + (idx >> 3), sl = idx & 7;
      gload16(Bb + (long)row * ldb + k0 + (sl ^ (row & 7)) * 8,
              (char*)&Bl[buf][0][0] + (half * (BN * 4) + l * 512 + wid * 64) * 16);
    }
  };

  f32x4 acc[8][2 * NH] = {};
  const int nk = K >> 6;

  stageB(0, 0, 0); stageB(0, 1, 0); stageA(0, 0, 0); stageA(0, 1, 0);
  if (nk > 1) { stageB(1, 0, 64); stageB(1, 1, 64); stageA(1, 0, 64); stageA(1, 1, 64); }
  if (nk > 1) {
    if constexpr (NH == 2) asm volatile("s_waitcnt vmcnt(8)" ::: "memory");
    else                   asm volatile("s_waitcnt vmcnt(6)" ::: "memory");
  } else {
    asm volatile("s_waitcnt vmcnt(0)" ::: "memory");
  }
  BARRIER_MEM;

  for (int kt = 0; kt < nk; ++kt) {
    const int b = kt & 1;
    const int k2 = (kt + 2) << 6;
    const bool pf = (kt + 2) < nk;

    // P0
    f16x8 a0[4][2], b0[NH][2];
#pragma unroll
    for (int m = 0; m < 4; ++m) {
      const int row = wr * 128 + m * 16 + ar;
#pragma unroll
      for (int ks = 0; ks < 2; ++ks)
        a0[m][ks] = *(const f16x8*)&Al[b][row][((ks * 4 + q4) ^ (row & 7)) * 8];
    }
#pragma unroll
    for (int n = 0; n < NH; ++n) {
      const int row = wn * WN + n * 16 + ar;
#pragma unroll
      for (int ks = 0; ks < 2; ++ks)
        b0[n][ks] = *(const f16x8*)&Bl[b][row][((ks * 4 + q4) ^ (row & 7)) * 8];
    }
    BARRIER_MEM;
    __builtin_amdgcn_s_setprio(1);
#pragma unroll
    for (int m = 0; m < 4; ++m)
#pragma unroll
      for (int n = 0; n < NH; ++n)
#pragma unroll
        for (int ks = 0; ks < 2; ++ks)
          acc[m][n] = __builtin_amdgcn_mfma_f32_16x16x32_f16(a0[m][ks], b0[n][ks], acc[m][n], 0, 0, 0);
    __builtin_amdgcn_s_setprio(0);
    BARRIER_MEM;

    // P1
    f16x8 b1f[NH][2];
#pragma unroll
    for (int n = 0; n < NH; ++n) {
      const int row = wn * WN + (n + NH) * 16 + ar;
#pragma unroll
      for (int ks = 0; ks < 2; ++ks)
        b1f[n][ks] = *(const f16x8*)&Bl[b][row][((ks * 4 + q4) ^ (row & 7)) * 8];
    }
    BARRIER_MEM;
    __builtin_amdgcn_s_setprio(1);
#pragma unroll
    for (int m = 0; m < 4; ++m)
#pragma unroll
      for (int n = 0; n < NH; ++n)
#pragma unroll
        for (int ks = 0; ks < 2; ++ks)
          acc[m][n + NH] = __builtin_amdgcn_mfma_f32_16x16x32_f16(a0[m][ks], b1f[n][ks], acc[m][n + NH], 0, 0, 0);
    __builtin_amdgcn_s_setprio(0);
    BARRIER_MEM;

    // P2
    f16x8 a1f[4][2];
#pragma unroll
    for (int m = 0; m < 4; ++m) {
      const int row = wr * 128 + (m + 4) * 16 + ar;
#pragma unroll
      for (int ks = 0; ks < 2; ++ks)
        a1f[m][ks] = *(const f16x8*)&Al[b][row][((ks * 4 + q4) ^ (row & 7)) * 8];
    }
    if (pf) { stageB(b, 0, k2); stageB(b, 1, k2); }
    BARRIER_MEM;
    __builtin_amdgcn_s_setprio(1);
#pragma unroll
    for (int m = 0; m < 4; ++m)
#pragma unroll
      for (int n = 0; n < NH; ++n)
#pragma unroll
        for (int ks = 0; ks < 2; ++ks)
          acc[m + 4][n] = __builtin_amdgcn_mfma_f32_16x16x32_f16(a1f[m][ks], b0[n][ks], acc[m + 4][n], 0, 0, 0);
    __builtin_amdgcn_s_setprio(0);
    BARRIER_MEM;

    // P3
    if (pf) { stageA(b, 0, k2); stageA(b, 1, k2); }
    __builtin_amdgcn_s_setprio(1);
#pragma unroll
    for (int m = 0; m < 4; ++m)
#pragma unroll
      for (int n = 0; n < NH; ++n)
#pragma unroll
        for (int ks = 0; ks < 2; ++ks)
          acc[m + 4][n + NH] = __builtin_amdgcn_mfma_f32_16x16x32_f16(a1f[m][ks], b1f[n][ks], acc[m + 4][n + NH], 0, 0, 0);
    __builtin_amdgcn_s_setprio(0);
    if (pf) {
      if constexpr (NH == 2) asm volatile("s_waitcnt vmcnt(8)" ::: "memory");
      else                   asm volatile("s_waitcnt vmcnt(6)" ::: "memory");
    } else if (kt + 1 < nk) {
      asm volatile("s_waitcnt vmcnt(0)" ::: "memory");
    }
    BARRIER_MEM;
  }

  // epilogue
#pragma unroll
  for (int m = 0; m < 8; ++m) {
#pragma unroll
    for (int n = 0; n < 2 * NH; ++n) {
      const int col = ny * BN + wn * WN + n * 16 + ar;
      float bv1 = 0.f, bv2 = 0.f;
      if (FLAGS & F_BIAS) bv1 = bias[col];
      if (FLAGS & F_DUAL) bv2 = bias2[col];
#pragma unroll
      for (int r = 0; r < 4; ++r) {
        const int row = mx * 256 + wr * 128 + m * 16 + q4 * 4 + r;
        float val = acc[m][n][r] + bv1;
        if (FLAGS & F_RELU) val = fmaxf(val, 0.f);
        if constexpr ((FLAGS & F_ACC) != 0) {
          float* p = (float*)Cv + (long)row * ldc + col;
          *p = *p + val;
        } else if constexpr ((FLAGS & F_OBF) != 0) {
          ((h16*)Cv)[(long)row * ldc + col] = (h16)val;
          if constexpr ((FLAGS & F_DUAL) != 0)
            ((h16*)C2v)[(long)row * ldc + col] = (h16)(acc[m][n][r] + bv2);
        } else {
          ((float*)Cv)[(long)row * ldc + col] = val;
        }
      }
    }
  }
}

// ---------------------------------------------------------------------------
// Fused Transformer-XL attention — r14 + setprio clusters + Psc stride 168.
// ---------------------------------------------------------------------------
__global__ __launch_bounds__(256) void fattn_k(
    const h16* __restrict__ qu, const h16* __restrict__ qv,
    const h16* __restrict__ kvb, const h16* __restrict__ vT,
    const h16* __restrict__ rb, h16* __restrict__ attn) {
  __shared__ h16 Kl[2][128][64];   // [j][d]  phys slot = (d_slot) ^ (j&7)
  __shared__ h16 Vl[64][128];      // [d][j]  phys slot = (j_slot) ^ (d&7)
  __shared__ h16 Psc[4][16][168];  // per-wave: band / P A-layout (336B rows, 16B-aligned)

  const int tid = threadIdx.x, lane = tid & 63, wv = tid >> 6;
  const int z = blockIdx.x, b = z >> 4, h = z & 15;
  const int i0 = blockIdx.y * 64;
  const int ar = lane & 15, q4 = lane >> 4;
  const int myrow = i0 + wv * 16;
  const h16* vTz = vT + (long)z * 64 * 1024;

  const long qoff = ((long)(myrow + ar) * 16 + b) * 1024 + h * 64 + q4 * 8;
  f16x8 quf[2], qvf[2];
  quf[0] = *(const f16x8*)&qu[qoff];
  quf[1] = *(const f16x8*)&qu[qoff + 32];
  qvf[0] = *(const f16x8*)&qv[qoff];
  qvf[1] = *(const f16x8*)&qv[qoff + 32];

  f32x4 o[4] = {};
  float lrow[4] = {0.f, 0.f, 0.f, 0.f};

  const int ntiles = (i0 + 575 + 128) >> 7;

  auto stageK = [&](int buf, int j0) {
#pragma unroll
    for (int it = 0; it < 4; ++it) {
      const int ch = it * 256 + wv * 64 + lane;
      const int kr = ch >> 3, ks = ch & 7;
      gload16(kvb + ((long)(j0 + kr) * 16 + b) * 2048 + h * 64 + (ks ^ (kr & 7)) * 8,
              (char*)&Kl[buf][0][0] + (it * 256 + wv * 64) * 16);
    }
  };
  auto stageV = [&](int j0) {
#pragma unroll
    for (int it = 0; it < 4; ++it) {
      const int ch = it * 256 + wv * 64 + lane;
      const int vd = ch >> 4, vs = ch & 15;
      gload16(vTz + (long)vd * 1024 + j0 + (vs ^ (vd & 7)) * 8,
              (char*)&Vl[0][0] + (it * 256 + wv * 64) * 16);
    }
  };

  stageK(0, 0);
  asm volatile("s_waitcnt vmcnt(0)" ::: "memory");
  __builtin_amdgcn_s_barrier();

  for (int t = 0; t < ntiles; ++t) {
    const int j0 = t * 128;
    const int kb = t & 1;
    const bool pk = (t + 1) < ntiles;

    stageV(j0);
    if (pk) stageK(kb ^ 1, (t + 1) * 128);
    if (pk) asm volatile("s_waitcnt vmcnt(8)" ::: "memory");
    else    asm volatile("s_waitcnt vmcnt(4)" ::: "memory");
    BARRIER_MEM;  // B0: all waves' K(t) visible

    f32x4 acc_c[8] = {};
    __builtin_amdgcn_s_setprio(1);
#pragma unroll
    for (int kd = 0; kd < 2; ++kd)
#pragma unroll
      for (int nf = 0; nf < 8; ++nf) {
        const int j = nf * 16 + ar;
        const int phys = (kd * 4 + q4) ^ (j & 7);
        const f16x8 kf = *(const f16x8*)&Kl[kb][j][phys * 8];
        acc_c[nf] = __builtin_amdgcn_mfma_f32_16x16x32_f16(quf[kd], kf, acc_c[nf], 0, 0, 0);
      }
    __builtin_amdgcn_s_setprio(0);

    const int jbase = j0 - myrow + 496;
    f32x4 acc_p[9] = {};
    __builtin_amdgcn_s_setprio(1);
#pragma unroll
    for (int kd = 0; kd < 2; ++kd)
#pragma unroll
      for (int jf = 0; jf < 9; ++jf) {
        int jjr = jbase + jf * 16 + ar;
        if (jjr > 1023) jjr = 1023;
        const f16x8 rf = *(const f16x8*)&rb[(long)jjr * 1024 + h * 64 + kd * 32 + q4 * 8];
        acc_p[jf] = __builtin_amdgcn_mfma_f32_16x16x32_f16(qvf[kd], rf, acc_p[jf], 0, 0, 0);
      }
    __builtin_amdgcn_s_setprio(0);
#pragma unroll
    for (int jf = 0; jf < 9; ++jf)
#pragma unroll
      for (int r = 0; r < 4; ++r)
        Psc[wv][q4 * 4 + r][jf * 16 + ar] = (h16)acc_p[jf][r];

    // ---- assemble S, fixed-max softmax (m = 0) ----
    float p[8][4];
#pragma unroll
    for (int nf = 0; nf < 8; ++nf)
#pragma unroll
      for (int r = 0; r < 4; ++r) {
        const int iloc = q4 * 4 + r;
        const int jloc = nf * 16 + ar;
        const int band = jloc - iloc + 15;
        const float pv = (float)Psc[wv][iloc][band];
        const float sv = (acc_c[nf][r] + pv) * 0.125f;
        const bool ok = (j0 + jloc) <= (myrow + iloc + 512);
        p[nf][r] = ok ? __expf(sv) : 0.f;
      }
#pragma unroll
    for (int r = 0; r < 4; ++r) {
      float ts = 0.f;
#pragma unroll
      for (int nf = 0; nf < 8; ++nf) ts += p[nf][r];
      ts += __shfl_xor(ts, 1);
      ts += __shfl_xor(ts, 2);
      ts += __shfl_xor(ts, 4);
      ts += __shfl_xor(ts, 8);
      lrow[r] += ts;
    }

#pragma unroll
    for (int nf = 0; nf < 8; ++nf)
#pragma unroll
      for (int r = 0; r < 4; ++r) {
        const int iloc = q4 * 4 + r, jloc = nf * 16 + ar;
        Psc[wv][iloc][((jloc >> 3) ^ (iloc & 7)) * 8 + (jloc & 7)] = (h16)p[nf][r];
      }

    if (pk) asm volatile("s_waitcnt vmcnt(4)" ::: "memory");
    else    asm volatile("s_waitcnt vmcnt(0)" ::: "memory");
    BARRIER_MEM;  // B1: all waves' V(t) visible; all past Kl[kb^1] reads

    __builtin_amdgcn_s_setprio(1);
#pragma unroll
    for (int ks = 0; ks < 4; ++ks) {
      const f16x8 pa = *(const f16x8*)&Psc[wv][ar][((ks * 4 + q4) ^ (ar & 7)) * 8];
#pragma unroll
      for (int vnf = 0; vnf < 4; ++vnf) {
        const int d = vnf * 16 + ar;
        const f16x8 vb = *(const f16x8*)&Vl[d][((ks * 4 + q4) ^ (d & 7)) * 8];
        o[vnf] = __builtin_amdgcn_mfma_f32_16x16x32_f16(pa, vb, o[vnf], 0, 0, 0);
      }
    }
    __builtin_amdgcn_s_setprio(0);
    BARRIER_MEM;  // B2: Vl free to overwrite
  }

#pragma unroll
  for (int vnf = 0; vnf < 4; ++vnf)
#pragma unroll
    for (int r = 0; r < 4; ++r) {
      const int i_ = myrow + q4 * 4 + r;
      attn[((long)i_ * 16 + b) * 1024 + h * 64 + vnf * 16 + ar] =
          (h16)(o[vnf][r] / lrow[r]);
    }
}

// ---------------------------------------------------------------------------
// Segmented weight transpose: all 6 f32(K,N)->h16(N,K) transposes, one launch.
// ---------------------------------------------------------------------------
__global__ __launch_bounds__(256) void wtransM_k(
    const float* __restrict__ Wkv, const float* __restrict__ Wq,
    const float* __restrict__ Wo, const float* __restrict__ Wp,
    const float* __restrict__ W1, const float* __restrict__ W2,
    h16* __restrict__ o0, h16* __restrict__ o1, h16* __restrict__ o2,
    h16* __restrict__ o3, h16* __restrict__ o4, h16* __restrict__ o5) {
  const int seg = blockIdx.y, t = blockIdx.x;
  int gx, gy, N, K;
  const float* in;
  h16* out;
  switch (seg) {
    case 0: gx = 64;  gy = 32;  in = Wkv; out = o0; N = 2048; K = 1024; break;
    case 1: gx = 32;  gy = 32;  in = Wq;  out = o1; N = 1024; K = 1024; break;
    case 2: gx = 32;  gy = 32;  in = Wo;  out = o2; N = 1024; K = 1024; break;
    case 3: gx = 32;  gy = 32;  in = Wp;  out = o3; N = 1024; K = 1024; break;
    case 4: gx = 128; gy = 32;  in = W1;  out = o4; N = 4096; K = 1024; break;
    default: gx = 32; gy = 128; in = W2;  out = o5; N = 1024; K = 4096; break;
  }
  if (t >= gx * gy) return;
  const int n0 = (t % gx) * 32, k0 = (t / gx) * 32;
  __shared__ float tb[32][33];
  const int tx = threadIdx.x & 31, ty = threadIdx.x >> 5;
#pragma unroll
  for (int j = 0; j < 32; j += 8)
    tb[ty + j][tx] = in[(long)(k0 + ty + j) * N + n0 + tx];
  __syncthreads();
#pragma unroll
  for (int j = 0; j < 32; j += 8)
    out[(long)(n0 + ty + j) * K + k0 + tx] = (h16)tb[tx][ty + j];
}

// build interleaved GRU gate weights: gB[3072][2048] h16
__global__ __launch_bounds__(256) void gateprep_k(
    const float* __restrict__ W1g, const float* __restrict__ U1g,
    const float* __restrict__ W2g, const float* __restrict__ U2g,
    h16* __restrict__ o1, h16* __restrict__ o2) {
  const long i = (long)blockIdx.x * 256 + threadIdx.x;
  const long elem = i * 4;
  const int row = (int)(elem >> 11);
  const int col = (int)(elem & 2047);
  const int gate = row >> 10, oc = row & 1023;
  const float* W = (blockIdx.y == 0) ? W1g : W2g;
  const float* U = (blockIdx.y == 0) ? U1g : U2g;
  h16* out = (blockIdx.y == 0) ? o1 : o2;
  const float* src = (col < 1024)
      ? (W + (long)gate * 1048576 + (long)oc * 1024 + col)
      : (U + (long)gate * 1048576 + (long)oc * 1024 + (col - 1024));
  const float4 v = *(const float4*)src;
  f16x4 o;
  o[0] = (h16)v.x; o[1] = (h16)v.y; o[2] = (h16)v.z; o[3] = (h16)v.w;
  *(f16x4*)(out + elem) = o;
}

// merged prep: seg0 = pos cast (1024 blocks), seg1 = xcast (8192), seg2 = addbias (4)
__global__ __launch_bounds__(256) void prep2_k(
    const float* __restrict__ pos, h16* __restrict__ posb,
    const float* __restrict__ inputs, h16* __restrict__ yx,
    const float* __restrict__ bq, const float* __restrict__ u,
    const float* __restrict__ v, float* __restrict__ qu, float* __restrict__ qv) {
  const int seg = blockIdx.y;
  if (seg == 0) {
    const long i = (long)blockIdx.x * 256 + threadIdx.x;
    if (i >= 262144) return;
    const float4 x = ((const float4*)pos)[i];
    f16x4 o;
    o[0] = (h16)x.x; o[1] = (h16)x.y; o[2] = (h16)x.z; o[3] = (h16)x.w;
    ((f16x4*)posb)[i] = o;
  } else if (seg == 1) {
    const long i = (long)blockIdx.x * 256 + threadIdx.x;
    const long row = i >> 8;
    const int c4 = (int)(i & 255);
    const float4 x = ((const float4*)inputs)[i];
    f16x4 o;
    o[0] = (h16)x.x; o[1] = (h16)x.y; o[2] = (h16)x.z; o[3] = (h16)x.w;
    *(f16x4*)(yx + row * 2048 + 1024 + c4 * 4) = o;
  } else {
    const int c = blockIdx.x * 256 + threadIdx.x;
    if (c < 1024) { qu[c] = bq[c] + u[c]; qv[c] = bq[c] + v[c]; }
  }
}

__global__ __launch_bounds__(256) void zero_out_k(float* __restrict__ out, long n) {
  const long i = (long)blockIdx.x * 256 + threadIdx.x;
  if (i < n) out[i] = 0.f;
}

__global__ __launch_bounds__(256) void ln_k(const float* __restrict__ src0,
                                            const float* __restrict__ src1, int rows0,
                                            const float* __restrict__ g,
                                            const float* __restrict__ b,
                                            h16* __restrict__ out) {
  const int row = blockIdx.x, tid = threadIdx.x;
  const float* src = (row < rows0) ? (src0 + (long)row * 1024)
                                   : (src1 + (long)(row - rows0) * 1024);
  const float4 x = ((const float4*)src)[tid];
  float s = x.x + x.y + x.z + x.w;
  float sq = x.x * x.x + x.y * x.y + x.z * x.z + x.w * x.w;
#pragma unroll
  for (int o = 32; o > 0; o >>= 1) { s += __shfl_down(s, o); sq += __shfl_down(sq, o); }
  __shared__ float red[8];
  const int lane = tid & 63, w = tid >> 6;
  if (lane == 0) { red[w] = s; red[4 + w] = sq; }
  __syncthreads();
  s = red[0] + red[1] + red[2] + red[3];
  sq = red[4] + red[5] + red[6] + red[7];
  const float mu = s * (1.f / 1024.f);
  const float inv = rsqrtf(sq * (1.f / 1024.f) - mu * mu + 1e-5f);
  const float4 gg = ((const float4*)g)[tid], bb = ((const float4*)b)[tid];
  f16x4 o;
  o[0] = (h16)((x.x - mu) * inv * gg.x + bb.x);
  o[1] = (h16)((x.y - mu) * inv * gg.y + bb.y);
  o[2] = (h16)((x.z - mu) * inv * gg.z + bb.z);
  o[3] = (h16)((x.w - mu) * inv * gg.w + bb.w);
  ((f16x4*)(out + (long)row * 1024))[tid] = o;
}

__global__ __launch_bounds__(256) void vtrans_k(const h16* __restrict__ kv,
                                                h16* __restrict__ vT) {
  const int z = blockIdx.y, b = z >> 4, h = z & 15;
  const int j0 = blockIdx.x * 64;
  __shared__ h16 t[64][72];
  const int jj = threadIdx.x >> 3, c = threadIdx.x & 7;
#pragma unroll
  for (int half = 0; half < 2; ++half) {
    const int j = jj + half * 32;
    const f16x8 v = *(const f16x8*)(kv + ((long)(j0 + j) * 16 + b) * 2048 + 1024 + h * 64 + c * 8);
    *(f16x8*)&t[j][c * 8] = v;
  }
  __syncthreads();
#pragma unroll
  for (int half = 0; half < 2; ++half) {
    const int d = jj + half * 32;
    f16x8 o;
#pragma unroll
    for (int k = 0; k < 8; ++k) o[k] = t[c * 8 + k][d];
    *(f16x8*)(vT + ((long)z * 64 + d) * 1024 + j0 + c * 8) = o;
  }
}

// rx = h16(sigmoid(Tr) * x); writes into x-half of yx (stride 2048)
template <typename XT>
__global__ __launch_bounds__(256) void gru_rx_k(const h16* __restrict__ T,
                                                const XT* __restrict__ x,
                                                h16* __restrict__ yx) {
  const long i = (long)blockIdx.x * 256 + threadIdx.x;
  const long row = i >> 8;
  const int c4 = (int)(i & 255);
  const f16x4 t = *(const f16x4*)(T + row * 2048 + c4 * 4);
  float xv[4];
  if constexpr (sizeof(XT) == 4) {
    const float4 xx = ((const float4*)x)[i];
    xv[0] = xx.x; xv[1] = xx.y; xv[2] = xx.z; xv[3] = xx.w;
  } else {
    const f16x4 xx = ((const f16x4*)x)[i];
    xv[0] = (float)xx[0]; xv[1] = (float)xx[1]; xv[2] = (float)xx[2]; xv[3] = (float)xx[3];
  }
  f16x4 o;
#pragma unroll
  for (int k = 0; k < 4; ++k)
    o[k] = (h16)(xv[k] / (1.f + __expf(-(float)t[k])));
  *(f16x4*)(yx + row * 2048 + 1024 + c4 * 4) = o;
}

// final gate: o = (1-z)*x + z*tanh(g) -> outf (f32 d_out); x in h16
__global__ __launch_bounds__(256) void gru_out_k(const h16* __restrict__ T,
                                                 const h16* __restrict__ G,
                                                 const h16* __restrict__ x,
                                                 const float* __restrict__ bg,
                                                 float* __restrict__ outf) {
  const long i = (long)blockIdx.x * 256 + threadIdx.x;
  const long row = i >> 8;
  const int c4 = (int)(i & 255);
  const f16x4 tz = *(const f16x4*)(T + row * 2048 + 1024 + c4 * 4);
  const f16x4 th = *(const f16x4*)(G + row * 1024 + c4 * 4);
  const f16x4 xx = ((const f16x4*)x)[i];
  const float4 bb = ((const float4*)bg)[c4];
  float4 o;
  {
    const float z0 = 1.f / (1.f + __expf(-((float)tz[0] - bb.x)));
    const float z1 = 1.f / (1.f + __expf(-((float)tz[1] - bb.y)));
    const float z2 = 1.f / (1.f + __expf(-((float)tz[2] - bb.z)));
    const float z3 = 1.f / (1.f + __expf(-((float)tz[3] - bb.w)));
    o.x = (1.f - z0) * (float)xx[0] + z0 * tanhf((float)th[0]);
    o.y = (1.f - z1) * (float)xx[1] + z1 * tanhf((float)th[1]);
    o.z = (1.f - z2) * (float)xx[2] + z2 * tanhf((float)th[2]);
    o.w = (1.f - z3) * (float)xx[3] + z3 * tanhf((float)th[3]);
  }
  ((float4*)outf)[i] = o;
}

// gate1 output + LN2 fused: block == row. Writes o1h (h16), yx2 x-half (h16),
// x2 (h16 LN(o)).
__global__ __launch_bounds__(256) void gruo_ln_k(
    const h16* __restrict__ T, const h16* __restrict__ G,
    const float* __restrict__ x, const float* __restrict__ bg,
    const float* __restrict__ lng, const float* __restrict__ lnb,
    h16* __restrict__ o1h, h16* __restrict__ yx2, h16* __restrict__ x2) {
  const int row = blockIdx.x, tid = threadIdx.x;
  const f16x4 tz = *(const f16x4*)(T + (long)row * 2048 + 1024 + tid * 4);
  const f16x4 th = *(const f16x4*)(G + (long)row * 1024 + tid * 4);
  const float4 xx = ((const float4*)(x + (long)row * 1024))[tid];
  const float4 bb = ((const float4*)bg)[tid];
  float4 o;
  {
    const float z0 = 1.f / (1.f + __expf(-((float)tz[0] - bb.x)));
    const float z1 = 1.f / (1.f + __expf(-((float)tz[1] - bb.y)));
    const float z2 = 1.f / (1.f + __expf(-((float)tz[2] - bb.z)));
    const float z3 = 1.f / (1.f + __expf(-((float)tz[3] - bb.w)));
    o.x = (1.f - z0) * xx.x + z0 * tanhf((float)th[0]);
    o.y = (1.f - z1) * xx.y + z1 * tanhf((float)th[1]);
    o.z = (1.f - z2) * xx.z + z2 * tanhf((float)th[2]);
    o.w = (1.f - z3) * xx.w + z3 * tanhf((float)th[3]);
  }
  {
    f16x4 oh;
    oh[0] = (h16)o.x; oh[1] = (h16)o.y; oh[2] = (h16)o.z; oh[3] = (h16)o.w;
    *(f16x4*)(o1h + (long)row * 1024 + tid * 4) = oh;
    *(f16x4*)(yx2 + (long)row * 2048 + 1024 + tid * 4) = oh;
  }
  // LN over the row
  float s = o.x + o.y + o.z + o.w;
  float sq = o.x * o.x + o.y * o.y + o.z * o.z + o.w * o.w;
#pragma unroll
  for (int off = 32; off > 0; off >>= 1) {
    s += __shfl_down(s, off);
    sq += __shfl_down(sq, off);
  }
  __shared__ float red[8];
  const int lane = tid & 63, wvi = tid >> 6;
  if (lane == 0) { red[wvi] = s; red[4 + wvi] = sq; }
  __syncthreads();
  s = red[0] + red[1] + red[2] + red[3];
  sq = red[4] + red[5] + red[6] + red[7];
  const float mu = s * (1.f / 1024.f);
  const float inv = rsqrtf(sq * (1.f / 1024.f) - mu * mu + 1e-5f);
  const float4 gg = ((const float4*)lng)[tid], bn = ((const float4*)lnb)[tid];
  f16x4 ol;
  ol[0] = (h16)((o.x - mu) * inv * gg.x + bn.x);
  ol[1] = (h16)((o.y - mu) * inv * gg.y + bn.y);
  ol[2] = (h16)((o.z - mu) * inv * gg.z + bn.z);
  ol[3] = (h16)((o.w - mu) * inv * gg.w + bn.w);
  *(f16x4*)(x2 + (long)row * 1024 + tid * 4) = ol;
}

// ---------------------------------------------------------------------------
extern "C" void kernel_launch(void* const* d_in, const int* in_sizes, int n_in,
                              void* d_out, int out_size, void* d_ws, size_t ws_size,
                              hipStream_t stream) {
  const float* inputs = (const float*)d_in[0];
  const float* pos    = (const float*)d_in[1];
  const float* u      = (const float*)d_in[2];
  const float* v      = (const float*)d_in[3];
  const float* memory = (const float*)d_in[4];
  const float* Wkv = (const float*)d_in[6];  const float* bkv = (const float*)d_in[7];
  const float* Wq  = (const float*)d_in[8];  const float* bq  = (const float*)d_in[9];
  const float* Wo  = (const float*)d_in[10]; const float* bo  = (const float*)d_in[11];
  const float* Wp  = (const float*)d_in[12]; const float* bp  = (const float*)d_in[13];
  const float* ln1_g = (const float*)d_in[14]; const float* ln1_b = (const float*)d_in[15];
  const float* ln2_g = (const float*)d_in[16]; const float* ln2_b = (const float*)d_in[17];
  const float* W1 = (const float*)d_in[18]; const float* b1 = (const float*)d_in[19];
  const float* W2 = (const float*)d_in[20]; const float* b2 = (const float*)d_in[21];
  const float* g1_W = (const float*)d_in[22]; const float* g1_U = (const float*)d_in[23];
  const float* g1_bg = (const float*)d_in[24];
  const float* g2_W = (const float*)d_in[25]; const float* g2_U = (const float*)d_in[26];
  const float* g2_bg = (const float*)d_in[27];
  (void)in_sizes; (void)n_in;

  const size_t MB = 1u << 20;
  const size_t NEEDED = 247 * MB;
  const dim3 blk(256);
  if (ws_size < NEEDED) {
    zero_out_k<<<(out_size + 255) / 256, blk, 0, stream>>>((float*)d_out, out_size);
    return;
  }

  char* w = (char*)d_ws;
  // --- static plan (liveness-checked; r13 layout) ---
  h16* WoT   = (h16*)(w + 0 * MB);     // 2
  h16* W1T   = (h16*)(w + 2 * MB);     // 8
  h16* W2T   = (h16*)(w + 10 * MB);    // 8
  h16* g1B   = (h16*)(w + 18 * MB);    // 12  [3072][2048]
  h16* g2B   = (h16*)(w + 30 * MB);    // 12
  h16* WkvT  = (h16*)(w + 42 * MB);    // 4
  h16* WqT   = (h16*)(w + 46 * MB);    // 2
  h16* WpT   = (h16*)(w + 48 * MB);    // 2
  h16* posb  = (h16*)(w + 50 * MB);    // 2
  float* bias_qu = (float*)(w + 52 * MB);
  float* bias_qv = (float*)(w + 52 * MB + 8192);
  h16* yx1   = (h16*)(w + 53 * MB);    // 32  [8192][2048]; prep->g1 gemm; x2
  h16* x1    = (h16*)(w + 85 * MB);    // 32  ln1->q | vT (attn) | yx2
  char* Rbig =        w + 117 * MB;    // 64  kvb | Trzh(32)+Tg(16) | h1(64)
  h16* qu    = (h16*)(w + 181 * MB);   // 16
  h16* qv    = (h16*)(w + 197 * MB);   // 16
  h16* attn  = (h16*)(w + 213 * MB);   // 16 | o1h h16 16MB
  h16* rb    = (h16*)(w + 245 * MB);   // 2
  // total 247

  h16*   kvb  = (h16*)Rbig;
  h16*   Trzh = (h16*)Rbig;                   // [8192][2048] h16 (gate phases)
  h16*   Tg   = (h16*)(Rbig + 32 * MB);       // [8192][1024] h16 (gate phases)
  h16*   h1   = (h16*)Rbig;                   // [8192][4096] h16 (MLP phase)
  h16*   vT   = x1;
  h16*   yx2  = x1;                           // [8192][2048] (vT dead post-fattn)
  h16*   o1h  = attn;                         // 16MB h16 (attn dead after Wo)
  h16*   x2   = yx1;                          // 16MB (yx1 dead after g1 gemm)

  // ---- weight prep ----
  wtransM_k<<<dim3(4096, 6), blk, 0, stream>>>(Wkv, Wq, Wo, Wp, W1, W2,
                                               WkvT, WqT, WoT, WpT, W1T, W2T);
  gateprep_k<<<dim3(6144, 2), blk, 0, stream>>>(g1_W, g1_U, g2_W, g2_U, g1B, g2B);
  prep2_k<<<dim3(8192, 3), blk, 0, stream>>>(pos, posb, inputs, yx1,
                                             bq, u, v, bias_qu, bias_qv);

  // ---- ln1 ----
  ln_k<<<16384, blk, 0, stream>>>(memory, inputs, 8192, ln1_g, ln1_b, x1);

  // ---- projections ----
  gemm2_k<256, F_OBF | F_BIAS><<<dim3(512), dim3(512), 0, stream>>>(
      x1, WkvT, kvb, bkv, 1024, 1024, 1024, 2048, 64, nullptr, nullptr);
  gemm2_k<128, F_OBF | F_BIAS | F_DUAL><<<dim3(256), dim3(512), 0, stream>>>(
      x1 + 8192L * 1024, WqT, qu, bias_qu, 1024, 1024, 1024, 1024, 32, qv, bias_qv);
  gemm2_k<128, F_OBF | F_BIAS><<<dim3(32), dim3(512), 0, stream>>>(
      posb, WpT, rb, bp, 1024, 1024, 1024, 1024, 4, nullptr, nullptr);
  vtrans_k<<<dim3(16, 256), blk, 0, stream>>>(kvb, vT);

  // ---- fused attention ----
  fattn_k<<<dim3(256, 8), blk, 0, stream>>>(qu, qv, kvb, vT, rb, attn);

  // ---- output projection + relu -> y-half of yx1 ----
  gemm2_k<128, F_OBF | F_BIAS | F_RELU><<<dim3(256), dim3(512), 0, stream>>>(
      attn, WoT, yx1, bo, 1024, 1024, 1024, 2048, 32, nullptr, nullptr);

  // ---- GRU gate 1: yx1 = [a1 | x-tilde] ----
  gemm2_k<256, F_OBF><<<dim3(256), dim3(512), 0, stream>>>(
      yx1, g1B, Trzh, nullptr, 2048, 2048, 2048, 2048, 32, nullptr, nullptr);
  gru_rx_k<float><<<8192, blk, 0, stream>>>(Trzh, inputs, yx1);   // rx1 -> x-half
  gemm2_k<128, F_OBF><<<dim3(256), dim3(512), 0, stream>>>(
      yx1, g1B + 2048L * 2048, Tg, nullptr, 2048, 2048, 2048, 1024, 32, nullptr, nullptr);
  // gate1 out + LN2 fused -> o1h, yx2 x-half, x2
  gruo_ln_k<<<8192, blk, 0, stream>>>(Trzh, Tg, inputs, g1_bg, ln2_g, ln2_b,
                                      o1h, yx2, x2);

  // ---- MLP ----
  gemm2_k<256, F_OBF | F_BIAS | F_RELU><<<dim3(512), dim3(512), 0, stream>>>(
      x2, W1T, h1, b1, 1024, 1024, 1024, 4096, 32, nullptr, nullptr);
  gemm2_k<128, F_OBF | F_BIAS | F_RELU><<<dim3(256), dim3(512), 0, stream>>>(
      h1, W2T, yx2, b2, 4096, 4096, 4096, 2048, 32, nullptr, nullptr);

  // ---- GRU gate 2: yx2 = [m2 | o1b] ----
  gemm2_k<256, F_OBF><<<dim3(256), dim3(512), 0, stream>>>(
      yx2, g2B, Trzh, nullptr, 2048, 2048, 2048, 2048, 32, nullptr, nullptr);
  gru_rx_k<h16><<<8192, blk, 0, stream>>>(Trzh, o1h, yx2);      // rx2 -> x-half
  gemm2_k<128, F_OBF><<<dim3(256), dim3(512), 0, stream>>>(
      yx2, g2B + 2048L * 2048, Tg, nullptr, 2048, 2048, 2048, 1024, 32, nullptr, nullptr);
  gru_out_k<<<8192, blk, 0, stream>>>(Trzh, Tg, o1h, g2_bg, (float*)d_out);
}

// Round 16
// 964.978 us; speedup vs baseline: 1.0132x; 1.0132x over previous
//
// GatedTransformerXLLayer — MI355X (gfx950) — round 16:
//   Recombination of measured-best pieces:
//   - fattn: r14 version VERBATIM (stride 164, no setprio). r15's setprio
//     (-12us, barrier-synced waves -> starves staging) and stride-168
//     (conflicts 6.5M->8.1M) both reverted.
//   - keep r15's prep2_k merge, h16 o1 end-to-end, templated gru_rx.
//
// D=1024 H=16 HD=64 HID=4096 CUR=512 PREV=512 FULL=1024 BS=16

#include <hip/hip_runtime.h>
#include <stdint.h>

typedef _Float16 h16;
typedef __attribute__((ext_vector_type(8))) _Float16 f16x8;
typedef __attribute__((ext_vector_type(4))) _Float16 f16x4;
typedef __attribute__((ext_vector_type(4))) float f32x4;

enum { F_OBF = 1, F_BIAS = 2, F_RELU = 4, F_ACC = 8, F_DUAL = 16 };

#define BARRIER_MEM                                  \
  do {                                               \
    asm volatile("" ::: "memory");                   \
    __builtin_amdgcn_s_barrier();                    \
    asm volatile("" ::: "memory");                   \
  } while (0)

static __device__ __forceinline__ void gload16(const void* g, void* l) {
  __builtin_amdgcn_global_load_lds((__attribute__((address_space(1))) void*)g,
                                   (__attribute__((address_space(3))) void*)l,
                                   16, 0, 0);
}

// ---------------------------------------------------------------------------
// gemm2_k: C = A(M x K) @ Bt(N x K)^T, 256 x BN tile, 8-phase pipeline
// (T2+T3+T4+T5). Grid: 1D nwg = (M/256)*(N/BN), nwg % 8 == 0, block 512.
// ---------------------------------------------------------------------------
template <int BN, int FLAGS>
__global__ __launch_bounds__(512) void gemm2_k(
    const h16* __restrict__ A, const h16* __restrict__ B,
    void* __restrict__ Cv, const float* __restrict__ bias,
    int K, int lda, int ldb, int ldc, int gm,
    void* __restrict__ C2v, const float* __restrict__ bias2) {
  constexpr int NH = BN / 128;
  constexpr int WN = BN / 4;
  __shared__ h16 Al[2][256][64];
  __shared__ h16 Bl[2][BN][64];

  const int tid = threadIdx.x, lane = tid & 63, wid = tid >> 6;
  const int wr = wid >> 2, wn = wid & 3;
  const int ar = lane & 15, q4 = lane >> 4;

  const int nwg = gridDim.x, cpx = nwg >> 3;
  const int bid = (blockIdx.x & 7) * cpx + (blockIdx.x >> 3);
  const int mx = bid % gm, ny = bid / gm;

  const h16* Ab = A + (long)mx * 256 * lda;
  const h16* Bb = B + (long)ny * BN * ldb;

  auto stageA = [&](int buf, int half, int k0) {
#pragma unroll
    for (int l = 0; l < 2; ++l) {
      const int idx = l * 512 + tid;
      const int row = half * 128 + (idx >> 3), sl = idx & 7;
      gload16(Ab + (long)row * lda + k0 + (sl ^ (row & 7)) * 8,
              (char*)&Al[buf][0][0] + (half * 1024 + l * 512 + wid * 64) * 16);
    }
  };
  auto stageB = [&](int buf, int half, int k0) {
#pragma unroll
    for (int l = 0; l < NH; ++l) {
      const int idx = l * 512 + tid;
      const int row = half * (BN / 2) + (idx >> 3), sl = idx & 7;
      gload16(Bb + (long)row * ldb + k0 + (sl ^ (row & 7)) * 8,
              (char*)&Bl[buf][0][0] + (half * (BN * 4) + l * 512 + wid * 64) * 16);
    }
  };

  f32x4 acc[8][2 * NH] = {};
  const int nk = K >> 6;

  stageB(0, 0, 0); stageB(0, 1, 0); stageA(0, 0, 0); stageA(0, 1, 0);
  if (nk > 1) { stageB(1, 0, 64); stageB(1, 1, 64); stageA(1, 0, 64); stageA(1, 1, 64); }
  if (nk > 1) {
    if constexpr (NH == 2) asm volatile("s_waitcnt vmcnt(8)" ::: "memory");
    else                   asm volatile("s_waitcnt vmcnt(6)" ::: "memory");
  } else {
    asm volatile("s_waitcnt vmcnt(0)" ::: "memory");
  }
  BARRIER_MEM;

  for (int kt = 0; kt < nk; ++kt) {
    const int b = kt & 1;
    const int k2 = (kt + 2) << 6;
    const bool pf = (kt + 2) < nk;

    // P0
    f16x8 a0[4][2], b0[NH][2];
#pragma unroll
    for (int m = 0; m < 4; ++m) {
      const int row = wr * 128 + m * 16 + ar;
#pragma unroll
      for (int ks = 0; ks < 2; ++ks)
        a0[m][ks] = *(const f16x8*)&Al[b][row][((ks * 4 + q4) ^ (row & 7)) * 8];
    }
#pragma unroll
    for (int n = 0; n < NH; ++n) {
      const int row = wn * WN + n * 16 + ar;
#pragma unroll
      for (int ks = 0; ks < 2; ++ks)
        b0[n][ks] = *(const f16x8*)&Bl[b][row][((ks * 4 + q4) ^ (row & 7)) * 8];
    }
    BARRIER_MEM;
    __builtin_amdgcn_s_setprio(1);
#pragma unroll
    for (int m = 0; m < 4; ++m)
#pragma unroll
      for (int n = 0; n < NH; ++n)
#pragma unroll
        for (int ks = 0; ks < 2; ++ks)
          acc[m][n] = __builtin_amdgcn_mfma_f32_16x16x32_f16(a0[m][ks], b0[n][ks], acc[m][n], 0, 0, 0);
    __builtin_amdgcn_s_setprio(0);
    BARRIER_MEM;

    // P1
    f16x8 b1f[NH][2];
#pragma unroll
    for (int n = 0; n < NH; ++n) {
      const int row = wn * WN + (n + NH) * 16 + ar;
#pragma unroll
      for (int ks = 0; ks < 2; ++ks)
        b1f[n][ks] = *(const f16x8*)&Bl[b][row][((ks * 4 + q4) ^ (row & 7)) * 8];
    }
    BARRIER_MEM;
    __builtin_amdgcn_s_setprio(1);
#pragma unroll
    for (int m = 0; m < 4; ++m)
#pragma unroll
      for (int n = 0; n < NH; ++n)
#pragma unroll
        for (int ks = 0; ks < 2; ++ks)
          acc[m][n + NH] = __builtin_amdgcn_mfma_f32_16x16x32_f16(a0[m][ks], b1f[n][ks], acc[m][n + NH], 0, 0, 0);
    __builtin_amdgcn_s_setprio(0);
    BARRIER_MEM;

    // P2
    f16x8 a1f[4][2];
#pragma unroll
    for (int m = 0; m < 4; ++m) {
      const int row = wr * 128 + (m + 4) * 16 + ar;
#pragma unroll
      for (int ks = 0; ks < 2; ++ks)
        a1f[m][ks] = *(const f16x8*)&Al[b][row][((ks * 4 + q4) ^ (row & 7)) * 8];
    }
    if (pf) { stageB(b, 0, k2); stageB(b, 1, k2); }
    BARRIER_MEM;
    __builtin_amdgcn_s_setprio(1);
#pragma unroll
    for (int m = 0; m < 4; ++m)
#pragma unroll
      for (int n = 0; n < NH; ++n)
#pragma unroll
        for (int ks = 0; ks < 2; ++ks)
          acc[m + 4][n] = __builtin_amdgcn_mfma_f32_16x16x32_f16(a1f[m][ks], b0[n][ks], acc[m + 4][n], 0, 0, 0);
    __builtin_amdgcn_s_setprio(0);
    BARRIER_MEM;

    // P3
    if (pf) { stageA(b, 0, k2); stageA(b, 1, k2); }
    __builtin_amdgcn_s_setprio(1);
#pragma unroll
    for (int m = 0; m < 4; ++m)
#pragma unroll
      for (int n = 0; n < NH; ++n)
#pragma unroll
        for (int ks = 0; ks < 2; ++ks)
          acc[m + 4][n + NH] = __builtin_amdgcn_mfma_f32_16x16x32_f16(a1f[m][ks], b1f[n][ks], acc[m + 4][n + NH], 0, 0, 0);
    __builtin_amdgcn_s_setprio(0);
    if (pf) {
      if constexpr (NH == 2) asm volatile("s_waitcnt vmcnt(8)" ::: "memory");
      else                   asm volatile("s_waitcnt vmcnt(6)" ::: "memory");
    } else if (kt + 1 < nk) {
      asm volatile("s_waitcnt vmcnt(0)" ::: "memory");
    }
    BARRIER_MEM;
  }

  // epilogue
#pragma unroll
  for (int m = 0; m < 8; ++m) {
#pragma unroll
    for (int n = 0; n < 2 * NH; ++n) {
      const int col = ny * BN + wn * WN + n * 16 + ar;
      float bv1 = 0.f, bv2 = 0.f;
      if (FLAGS & F_BIAS) bv1 = bias[col];
      if (FLAGS & F_DUAL) bv2 = bias2[col];
#pragma unroll
      for (int r = 0; r < 4; ++r) {
        const int row = mx * 256 + wr * 128 + m * 16 + q4 * 4 + r;
        float val = acc[m][n][r] + bv1;
        if (FLAGS & F_RELU) val = fmaxf(val, 0.f);
        if constexpr ((FLAGS & F_ACC) != 0) {
          float* p = (float*)Cv + (long)row * ldc + col;
          *p = *p + val;
        } else if constexpr ((FLAGS & F_OBF) != 0) {
          ((h16*)Cv)[(long)row * ldc + col] = (h16)val;
          if constexpr ((FLAGS & F_DUAL) != 0)
            ((h16*)C2v)[(long)row * ldc + col] = (h16)(acc[m][n][r] + bv2);
        } else {
          ((float*)Cv)[(long)row * ldc + col] = val;
        }
      }
    }
  }
}

// ---------------------------------------------------------------------------
// Fused Transformer-XL attention — r14 version VERBATIM (measured best):
// dbuf-K counted-vmcnt schedule, Psc stride 164, fixed-max softmax, no setprio.
// ---------------------------------------------------------------------------
__global__ __launch_bounds__(256) void fattn_k(
    const h16* __restrict__ qu, const h16* __restrict__ qv,
    const h16* __restrict__ kvb, const h16* __restrict__ vT,
    const h16* __restrict__ rb, h16* __restrict__ attn) {
  __shared__ h16 Kl[2][128][64];   // [j][d]  phys slot = (d_slot) ^ (j&7)
  __shared__ h16 Vl[64][128];      // [d][j]  phys slot = (j_slot) ^ (d&7)
  __shared__ h16 Psc[4][16][164];  // per-wave: band scores / P A-layout

  const int tid = threadIdx.x, lane = tid & 63, wv = tid >> 6;
  const int z = blockIdx.x, b = z >> 4, h = z & 15;
  const int i0 = blockIdx.y * 64;
  const int ar = lane & 15, q4 = lane >> 4;
  const int myrow = i0 + wv * 16;
  const h16* vTz = vT + (long)z * 64 * 1024;

  const long qoff = ((long)(myrow + ar) * 16 + b) * 1024 + h * 64 + q4 * 8;
  f16x8 quf[2], qvf[2];
  quf[0] = *(const f16x8*)&qu[qoff];
  quf[1] = *(const f16x8*)&qu[qoff + 32];
  qvf[0] = *(const f16x8*)&qv[qoff];
  qvf[1] = *(const f16x8*)&qv[qoff + 32];

  f32x4 o[4] = {};
  float lrow[4] = {0.f, 0.f, 0.f, 0.f};

  const int ntiles = (i0 + 575 + 128) >> 7;

  auto stageK = [&](int buf, int j0) {
#pragma unroll
    for (int it = 0; it < 4; ++it) {
      const int ch = it * 256 + wv * 64 + lane;
      const int kr = ch >> 3, ks = ch & 7;
      gload16(kvb + ((long)(j0 + kr) * 16 + b) * 2048 + h * 64 + (ks ^ (kr & 7)) * 8,
              (char*)&Kl[buf][0][0] + (it * 256 + wv * 64) * 16);
    }
  };
  auto stageV = [&](int j0) {
#pragma unroll
    for (int it = 0; it < 4; ++it) {
      const int ch = it * 256 + wv * 64 + lane;
      const int vd = ch >> 4, vs = ch & 15;
      gload16(vTz + (long)vd * 1024 + j0 + (vs ^ (vd & 7)) * 8,
              (char*)&Vl[0][0] + (it * 256 + wv * 64) * 16);
    }
  };

  stageK(0, 0);
  asm volatile("s_waitcnt vmcnt(0)" ::: "memory");
  __builtin_amdgcn_s_barrier();

  for (int t = 0; t < ntiles; ++t) {
    const int j0 = t * 128;
    const int kb = t & 1;
    const bool pk = (t + 1) < ntiles;

    stageV(j0);
    if (pk) stageK(kb ^ 1, (t + 1) * 128);
    if (pk) asm volatile("s_waitcnt vmcnt(8)" ::: "memory");
    else    asm volatile("s_waitcnt vmcnt(4)" ::: "memory");
    BARRIER_MEM;  // B0: all waves' K(t) visible

    f32x4 acc_c[8] = {};
#pragma unroll
    for (int kd = 0; kd < 2; ++kd)
#pragma unroll
      for (int nf = 0; nf < 8; ++nf) {
        const int j = nf * 16 + ar;
        const int phys = (kd * 4 + q4) ^ (j & 7);
        const f16x8 kf = *(const f16x8*)&Kl[kb][j][phys * 8];
        acc_c[nf] = __builtin_amdgcn_mfma_f32_16x16x32_f16(quf[kd], kf, acc_c[nf], 0, 0, 0);
      }

    const int jbase = j0 - myrow + 496;
    f32x4 acc_p[9] = {};
#pragma unroll
    for (int kd = 0; kd < 2; ++kd)
#pragma unroll
      for (int jf = 0; jf < 9; ++jf) {
        int jjr = jbase + jf * 16 + ar;
        if (jjr > 1023) jjr = 1023;
        const f16x8 rf = *(const f16x8*)&rb[(long)jjr * 1024 + h * 64 + kd * 32 + q4 * 8];
        acc_p[jf] = __builtin_amdgcn_mfma_f32_16x16x32_f16(qvf[kd], rf, acc_p[jf], 0, 0, 0);
      }
#pragma unroll
    for (int jf = 0; jf < 9; ++jf)
#pragma unroll
      for (int r = 0; r < 4; ++r)
        Psc[wv][q4 * 4 + r][jf * 16 + ar] = (h16)acc_p[jf][r];

    // ---- assemble S, fixed-max softmax (m = 0) ----
    float p[8][4];
#pragma unroll
    for (int nf = 0; nf < 8; ++nf)
#pragma unroll
      for (int r = 0; r < 4; ++r) {
        const int iloc = q4 * 4 + r;
        const int jloc = nf * 16 + ar;
        const int band = jloc - iloc + 15;
        const float pv = (float)Psc[wv][iloc][band];
        const float sv = (acc_c[nf][r] + pv) * 0.125f;
        const bool ok = (j0 + jloc) <= (myrow + iloc + 512);
        p[nf][r] = ok ? __expf(sv) : 0.f;
      }
#pragma unroll
    for (int r = 0; r < 4; ++r) {
      float ts = 0.f;
#pragma unroll
      for (int nf = 0; nf < 8; ++nf) ts += p[nf][r];
      ts += __shfl_xor(ts, 1);
      ts += __shfl_xor(ts, 2);
      ts += __shfl_xor(ts, 4);
      ts += __shfl_xor(ts, 8);
      lrow[r] += ts;
    }

#pragma unroll
    for (int nf = 0; nf < 8; ++nf)
#pragma unroll
      for (int r = 0; r < 4; ++r) {
        const int iloc = q4 * 4 + r, jloc = nf * 16 + ar;
        Psc[wv][iloc][((jloc >> 3) ^ (iloc & 7)) * 8 + (jloc & 7)] = (h16)p[nf][r];
      }

    if (pk) asm volatile("s_waitcnt vmcnt(4)" ::: "memory");
    else    asm volatile("s_waitcnt vmcnt(0)" ::: "memory");
    BARRIER_MEM;  // B1: all waves' V(t) visible; all past Kl[kb^1] reads

#pragma unroll
    for (int ks = 0; ks < 4; ++ks) {
      const f16x8 pa = *(const f16x8*)&Psc[wv][ar][((ks * 4 + q4) ^ (ar & 7)) * 8];
#pragma unroll
      for (int vnf = 0; vnf < 4; ++vnf) {
        const int d = vnf * 16 + ar;
        const f16x8 vb = *(const f16x8*)&Vl[d][((ks * 4 + q4) ^ (d & 7)) * 8];
        o[vnf] = __builtin_amdgcn_mfma_f32_16x16x32_f16(pa, vb, o[vnf], 0, 0, 0);
      }
    }
    BARRIER_MEM;  // B2: Vl free to overwrite
  }

#pragma unroll
  for (int vnf = 0; vnf < 4; ++vnf)
#pragma unroll
    for (int r = 0; r < 4; ++r) {
      const int i_ = myrow + q4 * 4 + r;
      attn[((long)i_ * 16 + b) * 1024 + h * 64 + vnf * 16 + ar] =
          (h16)(o[vnf][r] / lrow[r]);
    }
}

// ---------------------------------------------------------------------------
// Segmented weight transpose: all 6 f32(K,N)->h16(N,K) transposes, one launch.
// ---------------------------------------------------------------------------
__global__ __launch_bounds__(256) void wtransM_k(
    const float* __restrict__ Wkv, const float* __restrict__ Wq,
    const float* __restrict__ Wo, const float* __restrict__ Wp,
    const float* __restrict__ W1, const float* __restrict__ W2,
    h16* __restrict__ o0, h16* __restrict__ o1, h16* __restrict__ o2,
    h16* __restrict__ o3, h16* __restrict__ o4, h16* __restrict__ o5) {
  const int seg = blockIdx.y, t = blockIdx.x;
  int gx, gy, N, K;
  const float* in;
  h16* out;
  switch (seg) {
    case 0: gx = 64;  gy = 32;  in = Wkv; out = o0; N = 2048; K = 1024; break;
    case 1: gx = 32;  gy = 32;  in = Wq;  out = o1; N = 1024; K = 1024; break;
    case 2: gx = 32;  gy = 32;  in = Wo;  out = o2; N = 1024; K = 1024; break;
    case 3: gx = 32;  gy = 32;  in = Wp;  out = o3; N = 1024; K = 1024; break;
    case 4: gx = 128; gy = 32;  in = W1;  out = o4; N = 4096; K = 1024; break;
    default: gx = 32; gy = 128; in = W2;  out = o5; N = 1024; K = 4096; break;
  }
  if (t >= gx * gy) return;
  const int n0 = (t % gx) * 32, k0 = (t / gx) * 32;
  __shared__ float tb[32][33];
  const int tx = threadIdx.x & 31, ty = threadIdx.x >> 5;
#pragma unroll
  for (int j = 0; j < 32; j += 8)
    tb[ty + j][tx] = in[(long)(k0 + ty + j) * N + n0 + tx];
  __syncthreads();
#pragma unroll
  for (int j = 0; j < 32; j += 8)
    out[(long)(n0 + ty + j) * K + k0 + tx] = (h16)tb[tx][ty + j];
}

// build interleaved GRU gate weights: gB[3072][2048] h16
__global__ __launch_bounds__(256) void gateprep_k(
    const float* __restrict__ W1g, const float* __restrict__ U1g,
    const float* __restrict__ W2g, const float* __restrict__ U2g,
    h16* __restrict__ o1, h16* __restrict__ o2) {
  const long i = (long)blockIdx.x * 256 + threadIdx.x;
  const long elem = i * 4;
  const int row = (int)(elem >> 11);
  const int col = (int)(elem & 2047);
  const int gate = row >> 10, oc = row & 1023;
  const float* W = (blockIdx.y == 0) ? W1g : W2g;
  const float* U = (blockIdx.y == 0) ? U1g : U2g;
  h16* out = (blockIdx.y == 0) ? o1 : o2;
  const float* src = (col < 1024)
      ? (W + (long)gate * 1048576 + (long)oc * 1024 + col)
      : (U + (long)gate * 1048576 + (long)oc * 1024 + (col - 1024));
  const float4 v = *(const float4*)src;
  f16x4 o;
  o[0] = (h16)v.x; o[1] = (h16)v.y; o[2] = (h16)v.z; o[3] = (h16)v.w;
  *(f16x4*)(out + elem) = o;
}

// merged prep: seg0 = pos cast (1024 blocks), seg1 = xcast (8192), seg2 = addbias (4)
__global__ __launch_bounds__(256) void prep2_k(
    const float* __restrict__ pos, h16* __restrict__ posb,
    const float* __restrict__ inputs, h16* __restrict__ yx,
    const float* __restrict__ bq, const float* __restrict__ u,
    const float* __restrict__ v, float* __restrict__ qu, float* __restrict__ qv) {
  const int seg = blockIdx.y;
  if (seg == 0) {
    const long i = (long)blockIdx.x * 256 + threadIdx.x;
    if (i >= 262144) return;
    const float4 x = ((const float4*)pos)[i];
    f16x4 o;
    o[0] = (h16)x.x; o[1] = (h16)x.y; o[2] = (h16)x.z; o[3] = (h16)x.w;
    ((f16x4*)posb)[i] = o;
  } else if (seg == 1) {
    const long i = (long)blockIdx.x * 256 + threadIdx.x;
    const long row = i >> 8;
    const int c4 = (int)(i & 255);
    const float4 x = ((const float4*)inputs)[i];
    f16x4 o;
    o[0] = (h16)x.x; o[1] = (h16)x.y; o[2] = (h16)x.z; o[3] = (h16)x.w;
    *(f16x4*)(yx + row * 2048 + 1024 + c4 * 4) = o;
  } else {
    const int c = blockIdx.x * 256 + threadIdx.x;
    if (c < 1024) { qu[c] = bq[c] + u[c]; qv[c] = bq[c] + v[c]; }
  }
}

__global__ __launch_bounds__(256) void zero_out_k(float* __restrict__ out, long n) {
  const long i = (long)blockIdx.x * 256 + threadIdx.x;
  if (i < n) out[i] = 0.f;
}

__global__ __launch_bounds__(256) void ln_k(const float* __restrict__ src0,
                                            const float* __restrict__ src1, int rows0,
                                            const float* __restrict__ g,
                                            const float* __restrict__ b,
                                            h16* __restrict__ out) {
  const int row = blockIdx.x, tid = threadIdx.x;
  const float* src = (row < rows0) ? (src0 + (long)row * 1024)
                                   : (src1 + (long)(row - rows0) * 1024);
  const float4 x = ((const float4*)src)[tid];
  float s = x.x + x.y + x.z + x.w;
  float sq = x.x * x.x + x.y * x.y + x.z * x.z + x.w * x.w;
#pragma unroll
  for (int o = 32; o > 0; o >>= 1) { s += __shfl_down(s, o); sq += __shfl_down(sq, o); }
  __shared__ float red[8];
  const int lane = tid & 63, w = tid >> 6;
  if (lane == 0) { red[w] = s; red[4 + w] = sq; }
  __syncthreads();
  s = red[0] + red[1] + red[2] + red[3];
  sq = red[4] + red[5] + red[6] + red[7];
  const float mu = s * (1.f / 1024.f);
  const float inv = rsqrtf(sq * (1.f / 1024.f) - mu * mu + 1e-5f);
  const float4 gg = ((const float4*)g)[tid], bb = ((const float4*)b)[tid];
  f16x4 o;
  o[0] = (h16)((x.x - mu) * inv * gg.x + bb.x);
  o[1] = (h16)((x.y - mu) * inv * gg.y + bb.y);
  o[2] = (h16)((x.z - mu) * inv * gg.z + bb.z);
  o[3] = (h16)((x.w - mu) * inv * gg.w + bb.w);
  ((f16x4*)(out + (long)row * 1024))[tid] = o;
}

__global__ __launch_bounds__(256) void vtrans_k(const h16* __restrict__ kv,
                                                h16* __restrict__ vT) {
  const int z = blockIdx.y, b = z >> 4, h = z & 15;
  const int j0 = blockIdx.x * 64;
  __shared__ h16 t[64][72];
  const int jj = threadIdx.x >> 3, c = threadIdx.x & 7;
#pragma unroll
  for (int half = 0; half < 2; ++half) {
    const int j = jj + half * 32;
    const f16x8 v = *(const f16x8*)(kv + ((long)(j0 + j) * 16 + b) * 2048 + 1024 + h * 64 + c * 8);
    *(f16x8*)&t[j][c * 8] = v;
  }
  __syncthreads();
#pragma unroll
  for (int half = 0; half < 2; ++half) {
    const int d = jj + half * 32;
    f16x8 o;
#pragma unroll
    for (int k = 0; k < 8; ++k) o[k] = t[c * 8 + k][d];
    *(f16x8*)(vT + ((long)z * 64 + d) * 1024 + j0 + c * 8) = o;
  }
}

// rx = h16(sigmoid(Tr) * x); writes into x-half of yx (stride 2048)
template <typename XT>
__global__ __launch_bounds__(256) void gru_rx_k(const h16* __restrict__ T,
                                                const XT* __restrict__ x,
                                                h16* __restrict__ yx) {
  const long i = (long)blockIdx.x * 256 + threadIdx.x;
  const long row = i >> 8;
  const int c4 = (int)(i & 255);
  const f16x4 t = *(const f16x4*)(T + row * 2048 + c4 * 4);
  float xv[4];
  if constexpr (sizeof(XT) == 4) {
    const float4 xx = ((const float4*)x)[i];
    xv[0] = xx.x; xv[1] = xx.y; xv[2] = xx.z; xv[3] = xx.w;
  } else {
    const f16x4 xx = ((const f16x4*)x)[i];
    xv[0] = (float)xx[0]; xv[1] = (float)xx[1]; xv[2] = (float)xx[2]; xv[3] = (float)xx[3];
  }
  f16x4 o;
#pragma unroll
  for (int k = 0; k < 4; ++k)
    o[k] = (h16)(xv[k] / (1.f + __expf(-(float)t[k])));
  *(f16x4*)(yx + row * 2048 + 1024 + c4 * 4) = o;
}

// final gate: o = (1-z)*x + z*tanh(g) -> outf (f32 d_out); x in h16
__global__ __launch_bounds__(256) void gru_out_k(const h16* __restrict__ T,
                                                 const h16* __restrict__ G,
                                                 const h16* __restrict__ x,
                                                 const float* __restrict__ bg,
                                                 float* __restrict__ outf) {
  const long i = (long)blockIdx.x * 256 + threadIdx.x;
  const long row = i >> 8;
  const int c4 = (int)(i & 255);
  const f16x4 tz = *(const f16x4*)(T + row * 2048 + 1024 + c4 * 4);
  const f16x4 th = *(const f16x4*)(G + row * 1024 + c4 * 4);
  const f16x4 xx = ((const f16x4*)x)[i];
  const float4 bb = ((const float4*)bg)[c4];
  float4 o;
  {
    const float z0 = 1.f / (1.f + __expf(-((float)tz[0] - bb.x)));
    const float z1 = 1.f / (1.f + __expf(-((float)tz[1] - bb.y)));
    const float z2 = 1.f / (1.f + __expf(-((float)tz[2] - bb.z)));
    const float z3 = 1.f / (1.f + __expf(-((float)tz[3] - bb.w)));
    o.x = (1.f - z0) * (float)xx[0] + z0 * tanhf((float)th[0]);
    o.y = (1.f - z1) * (float)xx[1] + z1 * tanhf((float)th[1]);
    o.z = (1.f - z2) * (float)xx[2] + z2 * tanhf((float)th[2]);
    o.w = (1.f - z3) * (float)xx[3] + z3 * tanhf((float)th[3]);
  }
  ((float4*)outf)[i] = o;
}

// gate1 output + LN2 fused: block == row. Writes o1h (h16), yx2 x-half (h16),
// x2 (h16 LN(o)).
__global__ __launch_bounds__(256) void gruo_ln_k(
    const h16* __restrict__ T, const h16* __restrict__ G,
    const float* __restrict__ x, const float* __restrict__ bg,
    const float* __restrict__ lng, const float* __restrict__ lnb,
    h16* __restrict__ o1h, h16* __restrict__ yx2, h16* __restrict__ x2) {
  const int row = blockIdx.x, tid = threadIdx.x;
  const f16x4 tz = *(const f16x4*)(T + (long)row * 2048 + 1024 + tid * 4);
  const f16x4 th = *(const f16x4*)(G + (long)row * 1024 + tid * 4);
  const float4 xx = ((const float4*)(x + (long)row * 1024))[tid];
  const float4 bb = ((const float4*)bg)[tid];
  float4 o;
  {
    const float z0 = 1.f / (1.f + __expf(-((float)tz[0] - bb.x)));
    const float z1 = 1.f / (1.f + __expf(-((float)tz[1] - bb.y)));
    const float z2 = 1.f / (1.f + __expf(-((float)tz[2] - bb.z)));
    const float z3 = 1.f / (1.f + __expf(-((float)tz[3] - bb.w)));
    o.x = (1.f - z0) * xx.x + z0 * tanhf((float)th[0]);
    o.y = (1.f - z1) * xx.y + z1 * tanhf((float)th[1]);
    o.z = (1.f - z2) * xx.z + z2 * tanhf((float)th[2]);
    o.w = (1.f - z3) * xx.w + z3 * tanhf((float)th[3]);
  }
  {
    f16x4 oh;
    oh[0] = (h16)o.x; oh[1] = (h16)o.y; oh[2] = (h16)o.z; oh[3] = (h16)o.w;
    *(f16x4*)(o1h + (long)row * 1024 + tid * 4) = oh;
    *(f16x4*)(yx2 + (long)row * 2048 + 1024 + tid * 4) = oh;
  }
  // LN over the row
  float s = o.x + o.y + o.z + o.w;
  float sq = o.x * o.x + o.y * o.y + o.z * o.z + o.w * o.w;
#pragma unroll
  for (int off = 32; off > 0; off >>= 1) {
    s += __shfl_down(s, off);
    sq += __shfl_down(sq, off);
  }
  __shared__ float red[8];
  const int lane = tid & 63, wvi = tid >> 6;
  if (lane == 0) { red[wvi] = s; red[4 + wvi] = sq; }
  __syncthreads();
  s = red[0] + red[1] + red[2] + red[3];
  sq = red[4] + red[5] + red[6] + red[7];
  const float mu = s * (1.f / 1024.f);
  const float inv = rsqrtf(sq * (1.f / 1024.f) - mu * mu + 1e-5f);
  const float4 gg = ((const float4*)lng)[tid], bn = ((const float4*)lnb)[tid];
  f16x4 ol;
  ol[0] = (h16)((o.x - mu) * inv * gg.x + bn.x);
  ol[1] = (h16)((o.y - mu) * inv * gg.y + bn.y);
  ol[2] = (h16)((o.z - mu) * inv * gg.z + bn.z);
  ol[3] = (h16)((o.w - mu) * inv * gg.w + bn.w);
  *(f16x4*)(x2 + (long)row * 1024 + tid * 4) = ol;
}

// ---------------------------------------------------------------------------
extern "C" void kernel_launch(void* const* d_in, const int* in_sizes, int n_in,
                              void* d_out, int out_size, void* d_ws, size_t ws_size,
                              hipStream_t stream) {
  const float* inputs = (const float*)d_in[0];
  const float* pos    = (const float*)d_in[1];
  const float* u      = (const float*)d_in[2];
  const float* v      = (const float*)d_in[3];
  const float* memory = (const float*)d_in[4];
  const float* Wkv = (const float*)d_in[6];  const float* bkv = (const float*)d_in[7];
  const float* Wq  = (const float*)d_in[8];  const float* bq  = (const float*)d_in[9];
  const float* Wo  = (const float*)d_in[10]; const float* bo  = (const float*)d_in[11];
  const float* Wp  = (const float*)d_in[12]; const float* bp  = (const float*)d_in[13];
  const float* ln1_g = (const float*)d_in[14]; const float* ln1_b = (const float*)d_in[15];
  const float* ln2_g = (const float*)d_in[16]; const float* ln2_b = (const float*)d_in[17];
  const float* W1 = (const float*)d_in[18]; const float* b1 = (const float*)d_in[19];
  const float* W2 = (const float*)d_in[20]; const float* b2 = (const float*)d_in[21];
  const float* g1_W = (const float*)d_in[22]; const float* g1_U = (const float*)d_in[23];
  const float* g1_bg = (const float*)d_in[24];
  const float* g2_W = (const float*)d_in[25]; const float* g2_U = (const float*)d_in[26];
  const float* g2_bg = (const float*)d_in[27];
  (void)in_sizes; (void)n_in;

  const size_t MB = 1u << 20;
  const size_t NEEDED = 247 * MB;
  const dim3 blk(256);
  if (ws_size < NEEDED) {
    zero_out_k<<<(out_size + 255) / 256, blk, 0, stream>>>((float*)d_out, out_size);
    return;
  }

  char* w = (char*)d_ws;
  // --- static plan (liveness-checked; r13 layout) ---
  h16* WoT   = (h16*)(w + 0 * MB);     // 2
  h16* W1T   = (h16*)(w + 2 * MB);     // 8
  h16* W2T   = (h16*)(w + 10 * MB);    // 8
  h16* g1B   = (h16*)(w + 18 * MB);    // 12  [3072][2048]
  h16* g2B   = (h16*)(w + 30 * MB);    // 12
  h16* WkvT  = (h16*)(w + 42 * MB);    // 4
  h16* WqT   = (h16*)(w + 46 * MB);    // 2
  h16* WpT   = (h16*)(w + 48 * MB);    // 2
  h16* posb  = (h16*)(w + 50 * MB);    // 2
  float* bias_qu = (float*)(w + 52 * MB);
  float* bias_qv = (float*)(w + 52 * MB + 8192);
  h16* yx1   = (h16*)(w + 53 * MB);    // 32  [8192][2048]; prep->g1 gemm; x2
  h16* x1    = (h16*)(w + 85 * MB);    // 32  ln1->q | vT (attn) | yx2
  char* Rbig =        w + 117 * MB;    // 64  kvb | Trzh(32)+Tg(16) | h1(64)
  h16* qu    = (h16*)(w + 181 * MB);   // 16
  h16* qv    = (h16*)(w + 197 * MB);   // 16
  h16* attn  = (h16*)(w + 213 * MB);   // 16 | o1h h16 16MB
  h16* rb    = (h16*)(w + 245 * MB);   // 2
  // total 247

  h16*   kvb  = (h16*)Rbig;
  h16*   Trzh = (h16*)Rbig;                   // [8192][2048] h16 (gate phases)
  h16*   Tg   = (h16*)(Rbig + 32 * MB);       // [8192][1024] h16 (gate phases)
  h16*   h1   = (h16*)Rbig;                   // [8192][4096] h16 (MLP phase)
  h16*   vT   = x1;
  h16*   yx2  = x1;                           // [8192][2048] (vT dead post-fattn)
  h16*   o1h  = attn;                         // 16MB h16 (attn dead after Wo)
  h16*   x2   = yx1;                          // 16MB (yx1 dead after g1 gemm)

  // ---- weight prep ----
  wtransM_k<<<dim3(4096, 6), blk, 0, stream>>>(Wkv, Wq, Wo, Wp, W1, W2,
                                               WkvT, WqT, WoT, WpT, W1T, W2T);
  gateprep_k<<<dim3(6144, 2), blk, 0, stream>>>(g1_W, g1_U, g2_W, g2_U, g1B, g2B);
  prep2_k<<<dim3(8192, 3), blk, 0, stream>>>(pos, posb, inputs, yx1,
                                             bq, u, v, bias_qu, bias_qv);

  // ---- ln1 ----
  ln_k<<<16384, blk, 0, stream>>>(memory, inputs, 8192, ln1_g, ln1_b, x1);

  // ---- projections ----
  gemm2_k<256, F_OBF | F_BIAS><<<dim3(512), dim3(512), 0, stream>>>(
      x1, WkvT, kvb, bkv, 1024, 1024, 1024, 2048, 64, nullptr, nullptr);
  gemm2_k<128, F_OBF | F_BIAS | F_DUAL><<<dim3(256), dim3(512), 0, stream>>>(
      x1 + 8192L * 1024, WqT, qu, bias_qu, 1024, 1024, 1024, 1024, 32, qv, bias_qv);
  gemm2_k<128, F_OBF | F_BIAS><<<dim3(32), dim3(512), 0, stream>>>(
      posb, WpT, rb, bp, 1024, 1024, 1024, 1024, 4, nullptr, nullptr);
  vtrans_k<<<dim3(16, 256), blk, 0, stream>>>(kvb, vT);

  // ---- fused attention ----
  fattn_k<<<dim3(256, 8), blk, 0, stream>>>(qu, qv, kvb, vT, rb, attn);

  // ---- output projection + relu -> y-half of yx1 ----
  gemm2_k<128, F_OBF | F_BIAS | F_RELU><<<dim3(256), dim3(512), 0, stream>>>(
      attn, WoT, yx1, bo, 1024, 1024, 1024, 2048, 32, nullptr, nullptr);

  // ---- GRU gate 1: yx1 = [a1 | x-tilde] ----
  gemm2_k<256, F_OBF><<<dim3(256), dim3(512), 0, stream>>>(
      yx1, g1B, Trzh, nullptr, 2048, 2048, 2048, 2048, 32, nullptr, nullptr);
  gru_rx_k<float><<<8192, blk, 0, stream>>>(Trzh, inputs, yx1);   // rx1 -> x-half
  gemm2_k<128, F_OBF><<<dim3(256), dim3(512), 0, stream>>>(
      yx1, g1B + 2048L * 2048, Tg, nullptr, 2048, 2048, 2048, 1024, 32, nullptr, nullptr);
  // gate1 out + LN2 fused -> o1h, yx2 x-half, x2
  gruo_ln_k<<<8192, blk, 0, stream>>>(Trzh, Tg, inputs, g1_bg, ln2_g, ln2_b,
                                      o1h, yx2, x2);

  // ---- MLP ----
  gemm2_k<256, F_OBF | F_BIAS | F_RELU><<<dim3(512), dim3(512), 0, stream>>>(
      x2, W1T, h1, b1, 1024, 1024, 1024, 4096, 32, nullptr, nullptr);
  gemm2_k<128, F_OBF | F_BIAS | F_RELU><<<dim3(256), dim3(512), 0, stream>>>(
      h1, W2T, yx2, b2, 4096, 4096, 4096, 2048, 32, nullptr, nullptr);

  // ---- GRU gate 2: yx2 = [m2 | o1b] ----
  gemm2_k<256, F_OBF><<<dim3(256), dim3(512), 0, stream>>>(
      yx2, g2B, Trzh, nullptr, 2048, 2048, 2048, 2048, 32, nullptr, nullptr);
  gru_rx_k<h16><<<8192, blk, 0, stream>>>(Trzh, o1h, yx2);      // rx2 -> x-half
  gemm2_k<128, F_OBF><<<dim3(256), dim3(512), 0, stream>>>(
      yx2, g2B + 2048L * 2048, Tg, nullptr, 2048, 2048, 2048, 1024, 32, nullptr, nullptr);
  gru_out_k<<<8192, blk, 0, stream>>>(Trzh, Tg, o1h, g2_bg, (float*)d_out);
}